// Round 8
// baseline (125.430 us; speedup 1.0000x reference)
//
#include <hip/hip_runtime.h>
#include <math.h>

// Quantum circuit simulator: BATCH=2048 states x 1024 complex amplitudes,
// QDEPTH=8 layers of StronglyEntanglingLayers (10 Rot gates + 10 CNOTs).
//
// Round-8 structure: one wave per state, 16 complex amps/lane in registers,
// state staged in LDS as float2 at canonical padded pair-index
//     p(i) = 17*(i>>4) + (i&15)            (= i + (i>>4))
// (pad-17 keeps all transpose phases bank-balanced). Per layer, three LDS
// round trips (all ds_*_b64) re-localize bit groups so every Rot gate is
// register-local:
//   regs A: t = b3..b0  -> gates on wires 9,8,7,6
//   RT1 -> regs B: t' = b7..b4 -> gates on wires 5,4,3,2
//   RT2 -> regs C: t''= (b9,b8,b3,b2) -> gates on wires 1,0
//   RT3 -> write canonical, read with composed-CNOT permutation g folded in
//          (g is GF(2)-linear; generators computed inline per layer with the
//           round-6-validated perm loop).
// 96 DS insts/layer (vs 2048/wave in round 7's shuffle version) -- the DS
// pipe was the measured bottleneck (shuffles are DS ops on CDNA).
// No __syncthreads (single wave; per-wave DS ops are in-order).
// Gate coeffs precomputed by qprep into d_ws -> uniform scalar loads.

#define WIRES   10
#define NSTATE  1024
#define QDEPTH  8
#define NBATCH  2048
#define NGATES  (QDEPTH * WIRES)
#define WS_WORDS 640

// composed CNOT-stage permutation for range r: new[i] = old[g(i)],
// g = T_0 o T_1 o ... o T_9  (validated rounds 6/7)
__device__ __forceinline__ int perm_g(int j, int r) {
#pragma unroll
    for (int q = WIRES - 1; q >= 0; --q) {
        const int cb = 9 - q;
        const int tb = 9 - ((q + r) % WIRES);
        j ^= ((j >> cb) & 1) << tb;
    }
    return j;
}

__global__ __launch_bounds__(128) void qprep(
    const float* __restrict__ weights, float* __restrict__ ws)
{
    const int tid = threadIdx.x;
    if (tid < NGATES) {
        const float phi   = tanhf(weights[tid * 3 + 0]);
        const float theta = tanhf(weights[tid * 3 + 1]);
        const float omega = tanhf(weights[tid * 3 + 2]);
        const float c  = cosf(theta * 0.5f);
        const float sn = sinf(theta * 0.5f);
        const float a  = 0.5f * (phi + omega);
        const float bb = 0.5f * (phi - omega);
        const float ca = cosf(a),  sa = sinf(a);
        const float cb = cosf(bb), sb = sinf(bb);
        // U00 = e^{-ia} c ; U01 = -e^{+ib} s ; U10 = e^{-ib} s ; U11 = e^{+ia} c
        ws[tid * 8 + 0] =  ca * c;  ws[tid * 8 + 1] = -sa * c;
        ws[tid * 8 + 2] = -cb * sn; ws[tid * 8 + 3] = -sb * sn;
        ws[tid * 8 + 4] =  cb * sn; ws[tid * 8 + 5] = -sb * sn;
        ws[tid * 8 + 6] =  ca * c;  ws[tid * 8 + 7] =  sa * c;
    }
}

// apply one 2x2 gate to register pairs along local t-bit `mask`
#define APPLY_LOCAL(uptr, mask)                                               \
    {                                                                         \
        const float* __restrict__ u = (uptr);                                 \
        const float u00r = u[0], u00i = u[1], u01r = u[2], u01i = u[3];       \
        const float u10r = u[4], u10i = u[5], u11r = u[6], u11i = u[7];       \
        _Pragma("unroll")                                                     \
        for (int t0 = 0; t0 < 16; ++t0) {                                     \
            if (t0 & (mask)) continue;                                        \
            const int t1 = t0 | (mask);                                       \
            const float a0r = re[t0], a0i = im[t0];                           \
            const float a1r = re[t1], a1i = im[t1];                           \
            re[t0] = u00r*a0r - u00i*a0i + u01r*a1r - u01i*a1i;               \
            im[t0] = u00r*a0i + u00i*a0r + u01r*a1i + u01i*a1r;               \
            re[t1] = u10r*a0r - u10i*a0i + u11r*a1r - u11i*a1i;               \
            im[t1] = u10r*a0i + u10i*a0r + u11r*a1i + u11i*a1r;               \
        }                                                                     \
    }

__global__ __launch_bounds__(64) void qsim_wave(
    const float* __restrict__ x,
    const float* __restrict__ ws,
    float* __restrict__ out,
    const int interleaved)
{
    __shared__ float2 buf[1087];            // max p = 17*63+15 = 1086
    const int lane = threadIdx.x;           // 0..63
    const int b    = blockIdx.x;

    float re[16], im[16];

    // pair-index bases for the three access patterns
    const int pA = 17 * lane;                            // canonical (regs A)
    const int pB = 17 * (lane & 48) + (lane & 15);       // regs B gather
    const int pC = 17 * (lane >> 2) + (lane & 3);        // regs C gather

    // ---- load 16 contiguous amplitudes (real input, imag = 0) ----
    const float4* __restrict__ x4 =
        (const float4*)(x + ((size_t)b << 10) + (lane << 4));
#pragma unroll
    for (int k = 0; k < 4; ++k) {
        const float4 v = x4[k];
        re[4*k+0] = v.x; re[4*k+1] = v.y; re[4*k+2] = v.z; re[4*k+3] = v.w;
        im[4*k+0] = 0.f; im[4*k+1] = 0.f; im[4*k+2] = 0.f; im[4*k+3] = 0.f;
    }

    for (int l = 0; l < QDEPTH; ++l) {
        const float* __restrict__ gw = ws + l * 80;

        // ---- regs A: gates on wires 9,8,7,6 (t-bits 0..3) ----
        APPLY_LOCAL(gw + 9*8, 1)
        APPLY_LOCAL(gw + 8*8, 2)
        APPLY_LOCAL(gw + 7*8, 4)
        APPLY_LOCAL(gw + 6*8, 8)

        // ---- RT1: write canonical, gather regs B (t' = b7..b4) ----
#pragma unroll
        for (int t = 0; t < 16; ++t)
            buf[pA + t] = make_float2(re[t], im[t]);
#pragma unroll
        for (int t = 0; t < 16; ++t) {
            const float2 v = buf[pB + 17 * t];
            re[t] = v.x; im[t] = v.y;
        }

        // ---- regs B: gates on wires 5,4,3,2 (t'-bits 0..3) ----
        APPLY_LOCAL(gw + 5*8, 1)
        APPLY_LOCAL(gw + 4*8, 2)
        APPLY_LOCAL(gw + 3*8, 4)
        APPLY_LOCAL(gw + 2*8, 8)

        // ---- RT2: write back (same addrs), gather regs C (t''=(b9,b8,b3,b2)) ----
#pragma unroll
        for (int t = 0; t < 16; ++t)
            buf[pB + 17 * t] = make_float2(re[t], im[t]);
#pragma unroll
        for (int t = 0; t < 16; ++t) {
            const float2 v = buf[pC + 272 * (t >> 2) + 4 * (t & 3)];
            re[t] = v.x; im[t] = v.y;
        }

        // ---- regs C: gates on wires 1 (t''-bit2) and 0 (t''-bit3) ----
        APPLY_LOCAL(gw + 1*8, 4)
        APPLY_LOCAL(gw + 0*8, 8)

        // ---- RT3: write back (same addrs), read canonical with CNOT perm ----
#pragma unroll
        for (int t = 0; t < 16; ++t)
            buf[pC + 272 * (t >> 2) + 4 * (t & 3)] = make_float2(re[t], im[t]);

        // generators of g for this layer (wave-uniform)
        const int r = (l % (WIRES - 1)) + 1;
        int Gl[6], Gt[4];
#pragma unroll
        for (int jb = 0; jb < 6; ++jb) Gl[jb] = perm_g(1 << (4 + jb), r);
#pragma unroll
        for (int tb = 0; tb < 4; ++tb) Gt[tb] = perm_g(1 << tb, r);
        int glx = 0;
#pragma unroll
        for (int jb = 0; jb < 6; ++jb)
            glx ^= ((lane >> jb) & 1) ? Gl[jb] : 0;

#pragma unroll
        for (int t = 0; t < 16; ++t) {
            const int gt = ((t & 1) ? Gt[0] : 0) ^ ((t & 2) ? Gt[1] : 0) ^
                           ((t & 4) ? Gt[2] : 0) ^ ((t & 8) ? Gt[3] : 0);
            const int j = glx ^ gt;         // source amp = g(16*lane + t)
            const float2 v = buf[j + (j >> 4)];
            re[t] = v.x; im[t] = v.y;
        }
    }

    // ---- epilogue ----
    if (interleaved) {
        float2* __restrict__ o2 = (float2*)out;
#pragma unroll
        for (int t = 0; t < 16; ++t)
            o2[((size_t)b << 10) + (lane << 4) + t] = make_float2(re[t], im[t]);
    } else {
        // harness compares real part only (complex64 expected cast to float32)
        float4* __restrict__ o4 = (float4*)(out + ((size_t)b << 10) + (lane << 4));
#pragma unroll
        for (int k = 0; k < 4; ++k)
            o4[k] = make_float4(re[4*k+0], re[4*k+1], re[4*k+2], re[4*k+3]);
    }
}

// ---------------- validated round-6 fallback (ws too small) ----------------
__global__ __launch_bounds__(256) void qcircuit_kernel(
    const float* __restrict__ x, const float* __restrict__ weights,
    float* __restrict__ out, const int interleaved)
{
    __shared__ float s_re[NSTATE];
    __shared__ float s_im[NSTATE];
    __shared__ float s_g[NGATES][8];
    const int tid = threadIdx.x;
    const int b   = blockIdx.x;
    if (tid < NGATES) {
        const float phi   = tanhf(weights[tid * 3 + 0]);
        const float theta = tanhf(weights[tid * 3 + 1]);
        const float omega = tanhf(weights[tid * 3 + 2]);
        const float c  = cosf(theta * 0.5f);
        const float sn = sinf(theta * 0.5f);
        const float a  = 0.5f * (phi + omega);
        const float bb = 0.5f * (phi - omega);
        const float ca = cosf(a),  sa = sinf(a);
        const float cb = cosf(bb), sb = sinf(bb);
        s_g[tid][0] =  ca * c;  s_g[tid][1] = -sa * c;
        s_g[tid][2] = -cb * sn; s_g[tid][3] = -sb * sn;
        s_g[tid][4] =  cb * sn; s_g[tid][5] = -sb * sn;
        s_g[tid][6] =  ca * c;  s_g[tid][7] =  sa * c;
    }
#pragma unroll
    for (int k = 0; k < 4; ++k) {
        const int i = tid + 256 * k;
        s_re[i] = x[b * NSTATE + i];
        s_im[i] = 0.0f;
    }
    __syncthreads();
    for (int l = 0; l < QDEPTH; ++l) {
        for (int q = 0; q < WIRES; ++q) {
            const int gi = l * WIRES + q;
            const float u00r = s_g[gi][0], u00i = s_g[gi][1];
            const float u01r = s_g[gi][2], u01i = s_g[gi][3];
            const float u10r = s_g[gi][4], u10i = s_g[gi][5];
            const float u11r = s_g[gi][6], u11i = s_g[gi][7];
            const int sh = 9 - q;
            const int m  = 1 << sh;
#pragma unroll
            for (int k = 0; k < 2; ++k) {
                const int p  = tid + 256 * k;
                const int i0 = ((p >> sh) << (sh + 1)) | (p & (m - 1));
                const int i1 = i0 | m;
                const float a0r = s_re[i0], a0i = s_im[i0];
                const float a1r = s_re[i1], a1i = s_im[i1];
                s_re[i0] = u00r*a0r - u00i*a0i + u01r*a1r - u01i*a1i;
                s_im[i0] = u00r*a0i + u00i*a0r + u01r*a1i + u01i*a1r;
                s_re[i1] = u10r*a0r - u10i*a0i + u11r*a1r - u11i*a1i;
                s_im[i1] = u10r*a0i + u10i*a0r + u11r*a1i + u11i*a1r;
            }
            __syncthreads();
        }
        const int r = (l % (WIRES - 1)) + 1;
        float vr[4], vi[4];
#pragma unroll
        for (int k = 0; k < 4; ++k) {
            const int i = tid + 256 * k;
            const int j = perm_g(i, r);
            vr[k] = s_re[j]; vi[k] = s_im[j];
        }
        __syncthreads();
#pragma unroll
        for (int k = 0; k < 4; ++k) {
            const int i = tid + 256 * k;
            s_re[i] = vr[k]; s_im[i] = vi[k];
        }
        __syncthreads();
    }
    if (interleaved) {
#pragma unroll
        for (int k = 0; k < 4; ++k) {
            const int i  = tid + 256 * k;
            const int fi = 2 * (b * NSTATE + i);
            out[fi + 0] = s_re[i];
            out[fi + 1] = s_im[i];
        }
    } else {
#pragma unroll
        for (int k = 0; k < 4; ++k) {
            const int i = tid + 256 * k;
            out[b * NSTATE + i] = s_re[i];
        }
    }
}

extern "C" void kernel_launch(void* const* d_in, const int* in_sizes, int n_in,
                              void* d_out, int out_size, void* d_ws, size_t ws_size,
                              hipStream_t stream) {
    const float* x       = (const float*)d_in[0];   // (2048,1,32,32) f32
    const float* weights = (const float*)d_in[1];   // (8,10,3) f32
    float* out = (float*)d_out;
    const int interleaved = (out_size >= 2 * NBATCH * NSTATE) ? 1 : 0;

    if (ws_size >= WS_WORDS * sizeof(float)) {
        float* ws = (float*)d_ws;
        qprep<<<1, 128, 0, stream>>>(weights, ws);
        qsim_wave<<<NBATCH, 64, 0, stream>>>(x, ws, out, interleaved);
    } else {
        qcircuit_kernel<<<NBATCH, 256, 0, stream>>>(x, weights, out, interleaved);
    }
}

// Round 9
// 109.973 us; speedup vs baseline: 1.1406x; 1.1406x over previous
//
#include <hip/hip_runtime.h>
#include <math.h>

// Quantum circuit simulator: BATCH=2048 states x 1024 complex amplitudes,
// QDEPTH=8 layers of StronglyEntanglingLayers (10 Rot gates + 10 CNOTs).
//
// Round-9 structure = round-7 (validated, 66 us) with DS-pipe relief:
// one wave per state, 16 complex amps/lane (i = (lane<<4)|t), SoA b32 LDS.
//  - wires 9..6 (t-bits): register-local 2x2 updates.
//  - wires 5,4,3,2 (lane XOR 1,2,4,8): partner fetch via DPP row ops on the
//    VALU pipe (quad_perm / mirrors / row_ror:8) -- zero DS instructions.
//    (Round 7 used ds-pipe shuffles for these; DS was the measured
//    bottleneck at ~40 us. Round 8's b64/float2 LDS variant regressed:
//    pair-packed layout puts .x on even banks only -> structural 4-way
//    conflicts, SQ_LDS_BANK_CONFLICT 7.3e6. Reverted.)
//  - wires 1,0 (lane XOR 16,32): cross-row, keep __shfl_xor.
//  - CNOT stage: composed GF(2)-linear permutation via one LDS round trip,
//    t-major layout word(i) = (i&15)*64 + (i>>4) (bank = lane mod 32,
//    measured conflict-free), XOR-decomposed address tables in d_ws.
// No __syncthreads (single wave; per-wave DS ops are in-order).

#define WIRES   10
#define NSTATE  1024
#define QDEPTH  8
#define NBATCH  2048
#define NGATES  (QDEPTH * WIRES)

// ws layout (floats/ints, 4 B each):
//   [0   .. 640)  gate coeffs: gate gi=(l*10+q): u00r,u00i,u01r,u01i,u10r,u10i,u11r,u11i
//   [640 .. 768)  int gt[l*16+t]    = word(g_l(t))
//   [768 .. 1280) int glane[l*64+v] = word(g_l(v<<4))
#define WS_WORDS 1280

__device__ __forceinline__ int perm_g(int j, int r) {
#pragma unroll
    for (int q = WIRES - 1; q >= 0; --q) {
        const int cb = 9 - q;
        const int tb = 9 - ((q + r) % WIRES);
        j ^= ((j >> cb) & 1) << tb;
    }
    return j;
}

__global__ __launch_bounds__(1024) void qprep(
    const float* __restrict__ weights, float* __restrict__ ws)
{
    const int tid = threadIdx.x;
    if (tid < NGATES) {
        const float phi   = tanhf(weights[tid * 3 + 0]);
        const float theta = tanhf(weights[tid * 3 + 1]);
        const float omega = tanhf(weights[tid * 3 + 2]);
        const float c  = cosf(theta * 0.5f);
        const float sn = sinf(theta * 0.5f);
        const float a  = 0.5f * (phi + omega);
        const float bb = 0.5f * (phi - omega);
        const float ca = cosf(a),  sa = sinf(a);
        const float cb = cosf(bb), sb = sinf(bb);
        // U00 = e^{-ia} c ; U01 = -e^{+ib} s ; U10 = e^{-ib} s ; U11 = e^{+ia} c
        ws[tid * 8 + 0] =  ca * c;  ws[tid * 8 + 1] = -sa * c;
        ws[tid * 8 + 2] = -cb * sn; ws[tid * 8 + 3] = -sb * sn;
        ws[tid * 8 + 4] =  cb * sn; ws[tid * 8 + 5] = -sb * sn;
        ws[tid * 8 + 6] =  ca * c;  ws[tid * 8 + 7] =  sa * c;
    }
    int* wsI = (int*)ws;
    if (tid >= 128 && tid < 256) {          // gt table: 8 layers x 16 t
        const int e = tid - 128, l = e >> 4, t = e & 15;
        const int j = perm_g(t, (l % (WIRES - 1)) + 1);
        wsI[640 + e] = ((j & 15) << 6) | (j >> 4);
    }
    if (tid >= 256 && tid < 768) {          // glane table: 8 layers x 64 lanes
        const int e = tid - 256, l = e >> 6, v = e & 63;
        const int j = perm_g(v << 4, (l % (WIRES - 1)) + 1);
        wsI[768 + e] = ((j & 15) << 6) | (j >> 4);
    }
}

// DPP cross-lane move (VALU pipe, within rows of 16 lanes)
template<int CTRL>
__device__ __forceinline__ float dppmov(float x) {
    return __int_as_float(__builtin_amdgcn_update_dpp(
        0, __float_as_int(x), CTRL, 0xF, 0xF, true));
}
// XOR1 = quad_perm[1,0,3,2]; XOR2 = quad_perm[2,3,0,1];
// XOR4 = half_mirror(i^7) o quad_perm[3,2,1,0](i^3) -- both self-inverse;
// XOR8 = row_ror:8 ((i+-8) mod 16 == i^8, direction-independent)
#define FX1(v)  dppmov<0xB1>(v)
#define FX2(v)  dppmov<0x4E>(v)
#define FX4(v)  dppmov<0x1B>(dppmov<0x141>(v))
#define FX8(v)  dppmov<0x128>(v)
#define FX16(v) __shfl_xor((v), 16, 64)
#define FX32(v) __shfl_xor((v), 32, 64)

// gate on lane-bit J (wire W), partner value via FETCH
#define LANE_GATE(W, J, FETCH)                                                \
    {                                                                         \
        const float* __restrict__ u = gw + (W) * 8;                           \
        const bool hi = (lane >> (J)) & 1;                                    \
        const float c0r = hi ? u[6] : u[0], c0i = hi ? u[7] : u[1];           \
        const float c1r = hi ? u[4] : u[2], c1i = hi ? u[5] : u[3];           \
        _Pragma("unroll")                                                     \
        for (int t = 0; t < 16; ++t) {                                        \
            const float pr = FETCH(re[t]);                                    \
            const float pi = FETCH(im[t]);                                    \
            const float sr = re[t], si = im[t];                               \
            re[t] = c0r*sr - c0i*si + c1r*pr - c1i*pi;                        \
            im[t] = c0r*si + c0i*sr + c1r*pi + c1i*pr;                        \
        }                                                                     \
    }

__global__ __launch_bounds__(64) void qsim_wave(
    const float* __restrict__ x,
    const float* __restrict__ ws,
    float* __restrict__ out,
    const int interleaved)
{
    __shared__ float lre[NSTATE];
    __shared__ float lim[NSTATE];
    const int lane = threadIdx.x;           // 0..63
    const int b    = blockIdx.x;
    const int* __restrict__ wsI = (const int*)ws;

    float re[16], im[16];

    // ---- load 16 contiguous amplitudes (real input, imag = 0) ----
    const float4* __restrict__ x4 =
        (const float4*)(x + ((size_t)b << 10) + (lane << 4));
#pragma unroll
    for (int k = 0; k < 4; ++k) {
        const float4 v = x4[k];
        re[4*k+0] = v.x; re[4*k+1] = v.y; re[4*k+2] = v.z; re[4*k+3] = v.w;
        im[4*k+0] = 0.f; im[4*k+1] = 0.f; im[4*k+2] = 0.f; im[4*k+3] = 0.f;
    }

    for (int l = 0; l < QDEPTH; ++l) {
        const float* __restrict__ gw = ws + l * 80;

        // ---- local-bit gates: t-bits 0..3 = wires 9..6 (register-only) ----
#pragma unroll
        for (int bb = 0; bb < 4; ++bb) {
            const float* __restrict__ u = gw + (9 - bb) * 8;
            const float u00r = u[0], u00i = u[1], u01r = u[2], u01i = u[3];
            const float u10r = u[4], u10i = u[5], u11r = u[6], u11i = u[7];
#pragma unroll
            for (int t0 = 0; t0 < 16; ++t0) {
                if (t0 & (1 << bb)) continue;
                const int t1 = t0 | (1 << bb);
                const float a0r = re[t0], a0i = im[t0];
                const float a1r = re[t1], a1i = im[t1];
                re[t0] = u00r*a0r - u00i*a0i + u01r*a1r - u01i*a1i;
                im[t0] = u00r*a0i + u00i*a0r + u01r*a1i + u01i*a1r;
                re[t1] = u10r*a0r - u10i*a0i + u11r*a1r - u11i*a1i;
                im[t1] = u10r*a0i + u10i*a0r + u11r*a1i + u11i*a1r;
            }
        }

        // ---- lane-bit gates: wires 5..2 on VALU (DPP), wires 1,0 via shfl ----
        LANE_GATE(5, 0, FX1)
        LANE_GATE(4, 1, FX2)
        LANE_GATE(3, 2, FX4)
        LANE_GATE(2, 3, FX8)
        LANE_GATE(1, 4, FX16)
        LANE_GATE(0, 5, FX32)

        // ---- CNOT stage: new[i] = old[g(i)] via one LDS round trip ----
        // write own amps at word(i) = t*64 + lane (bank = lane mod 32: free)
#pragma unroll
        for (int t = 0; t < 16; ++t) {
            lre[t * 64 + lane] = re[t];
            lim[t * 64 + lane] = im[t];
        }
        // single wave: per-wave DS ops execute in order; no barrier needed
        const int ga = wsI[768 + l * 64 + lane];    // word(g(lane<<4))
#pragma unroll
        for (int t = 0; t < 16; ++t) {
            const int a = ga ^ wsI[640 + l * 16 + t];   // ^ word(g(t))
            re[t] = lre[a];
            im[t] = lim[a];
        }
    }

    // ---- epilogue ----
    if (interleaved) {
        float2* __restrict__ o2 = (float2*)out;
#pragma unroll
        for (int t = 0; t < 16; ++t)
            o2[((size_t)b << 10) + (lane << 4) + t] = make_float2(re[t], im[t]);
    } else {
        // harness compares real part only (complex64 expected cast to float32)
        float4* __restrict__ o4 = (float4*)(out + ((size_t)b << 10) + (lane << 4));
#pragma unroll
        for (int k = 0; k < 4; ++k)
            o4[k] = make_float4(re[4*k+0], re[4*k+1], re[4*k+2], re[4*k+3]);
    }
}

// ---------------- validated round-6 fallback (ws too small) ----------------
__global__ __launch_bounds__(256) void qcircuit_kernel(
    const float* __restrict__ x, const float* __restrict__ weights,
    float* __restrict__ out, const int interleaved)
{
    __shared__ float s_re[NSTATE];
    __shared__ float s_im[NSTATE];
    __shared__ float s_g[NGATES][8];
    const int tid = threadIdx.x;
    const int b   = blockIdx.x;
    if (tid < NGATES) {
        const float phi   = tanhf(weights[tid * 3 + 0]);
        const float theta = tanhf(weights[tid * 3 + 1]);
        const float omega = tanhf(weights[tid * 3 + 2]);
        const float c  = cosf(theta * 0.5f);
        const float sn = sinf(theta * 0.5f);
        const float a  = 0.5f * (phi + omega);
        const float bb = 0.5f * (phi - omega);
        const float ca = cosf(a),  sa = sinf(a);
        const float cb = cosf(bb), sb = sinf(bb);
        s_g[tid][0] =  ca * c;  s_g[tid][1] = -sa * c;
        s_g[tid][2] = -cb * sn; s_g[tid][3] = -sb * sn;
        s_g[tid][4] =  cb * sn; s_g[tid][5] = -sb * sn;
        s_g[tid][6] =  ca * c;  s_g[tid][7] =  sa * c;
    }
#pragma unroll
    for (int k = 0; k < 4; ++k) {
        const int i = tid + 256 * k;
        s_re[i] = x[b * NSTATE + i];
        s_im[i] = 0.0f;
    }
    __syncthreads();
    for (int l = 0; l < QDEPTH; ++l) {
        for (int q = 0; q < WIRES; ++q) {
            const int gi = l * WIRES + q;
            const float u00r = s_g[gi][0], u00i = s_g[gi][1];
            const float u01r = s_g[gi][2], u01i = s_g[gi][3];
            const float u10r = s_g[gi][4], u10i = s_g[gi][5];
            const float u11r = s_g[gi][6], u11i = s_g[gi][7];
            const int sh = 9 - q;
            const int m  = 1 << sh;
#pragma unroll
            for (int k = 0; k < 2; ++k) {
                const int p  = tid + 256 * k;
                const int i0 = ((p >> sh) << (sh + 1)) | (p & (m - 1));
                const int i1 = i0 | m;
                const float a0r = s_re[i0], a0i = s_im[i0];
                const float a1r = s_re[i1], a1i = s_im[i1];
                s_re[i0] = u00r*a0r - u00i*a0i + u01r*a1r - u01i*a1i;
                s_im[i0] = u00r*a0i + u00i*a0r + u01r*a1i + u01i*a1r;
                s_re[i1] = u10r*a0r - u10i*a0i + u11r*a1r - u11i*a1i;
                s_im[i1] = u10r*a0i + u10i*a0r + u11r*a1i + u11i*a1r;
            }
            __syncthreads();
        }
        const int r = (l % (WIRES - 1)) + 1;
        float vr[4], vi[4];
#pragma unroll
        for (int k = 0; k < 4; ++k) {
            const int i = tid + 256 * k;
            const int j = perm_g(i, r);
            vr[k] = s_re[j]; vi[k] = s_im[j];
        }
        __syncthreads();
#pragma unroll
        for (int k = 0; k < 4; ++k) {
            const int i = tid + 256 * k;
            s_re[i] = vr[k]; s_im[i] = vi[k];
        }
        __syncthreads();
    }
    if (interleaved) {
#pragma unroll
        for (int k = 0; k < 4; ++k) {
            const int i  = tid + 256 * k;
            const int fi = 2 * (b * NSTATE + i);
            out[fi + 0] = s_re[i];
            out[fi + 1] = s_im[i];
        }
    } else {
#pragma unroll
        for (int k = 0; k < 4; ++k) {
            const int i = tid + 256 * k;
            out[b * NSTATE + i] = s_re[i];
        }
    }
}

extern "C" void kernel_launch(void* const* d_in, const int* in_sizes, int n_in,
                              void* d_out, int out_size, void* d_ws, size_t ws_size,
                              hipStream_t stream) {
    const float* x       = (const float*)d_in[0];   // (2048,1,32,32) f32
    const float* weights = (const float*)d_in[1];   // (8,10,3) f32
    float* out = (float*)d_out;
    const int interleaved = (out_size >= 2 * NBATCH * NSTATE) ? 1 : 0;

    if (ws_size >= WS_WORDS * sizeof(float)) {
        float* ws = (float*)d_ws;
        qprep<<<1, 1024, 0, stream>>>(weights, ws);
        qsim_wave<<<NBATCH, 64, 0, stream>>>(x, ws, out, interleaved);
    } else {
        qcircuit_kernel<<<NBATCH, 256, 0, stream>>>(x, weights, out, interleaved);
    }
}

// Round 10
// 108.659 us; speedup vs baseline: 1.1543x; 1.0121x over previous
//
#include <hip/hip_runtime.h>
#include <math.h>

// Quantum circuit simulator: BATCH=2048 states x 1024 complex amplitudes,
// QDEPTH=8 layers of StronglyEntanglingLayers (10 Rot gates + 10 CNOTs).
//
// Round-10 structure: TWO waves per state (block=128), 8 complex amps/lane,
//   i = (w<<9) | (lane<<3) | t      (w = wave bit = wire 0)
// Rationale (r7/r9 counters): VALU busy time is ~37us structural; at 1
// wave/state the grid gives only 2 waves/SIMD (Occupancy 18%) so DS and
// VALU barely overlap (53.5 ~= 37+20 serial). Doubling waves/SIMD fills
// the idle. Gate placement:
//  - wires 9,8,7 (t-bits 0,1,2): register-local 2x2 updates.
//  - wires 6,5,4,3 (lane xor 1,2,4,8): DPP row ops (VALU pipe, r9-validated).
//  - wires 2,1 (lane xor 16,32): __shfl_xor (intra-wave, DS pipe).
//  - wire 0 (wave bit 9): FOLDED into the CNOT LDS round trip:
//      new[i] = c0*psi[g(i)] + c1*psi[g(i)^512],  c's by bit9 of g(i),
//    where g = composed GF(2)-linear CNOT permutation (validated r6-r9).
// LDS stage: lane-major SoA, contiguous b128 writes, scattered b32 reads.
// 2 __syncthreads per layer (2-wave blocks: cheap).
// Address tables + gate coeffs precomputed into d_ws by qprep.

#define WIRES   10
#define NSTATE  1024
#define QDEPTH  8
#define NBATCH  2048
#define NGATES  (QDEPTH * WIRES)

// ws layout (4-B words):
//   [0    .. 640)   gate coeffs: gate (l*10+q): u00r,u00i,u01r,u01i,u10r,u10i,u11r,u11i
//   [640  .. 704)   int gt[l*8 + t]     = g_l(t)                 (t-bit part)
//   [704  .. 1728)  int gl[l*128 + tid] = g_l((tid>>6)<<9 | (tid&63)<<3)
#define WS_WORDS 1728

__device__ __forceinline__ int perm_g(int j, int r) {
#pragma unroll
    for (int q = WIRES - 1; q >= 0; --q) {
        const int cb = 9 - q;
        const int tb = 9 - ((q + r) % WIRES);
        j ^= ((j >> cb) & 1) << tb;
    }
    return j;
}

__global__ __launch_bounds__(1024) void qprep(
    const float* __restrict__ weights, float* __restrict__ ws)
{
    const int tid = threadIdx.x;
    if (tid < NGATES) {
        const float phi   = tanhf(weights[tid * 3 + 0]);
        const float theta = tanhf(weights[tid * 3 + 1]);
        const float omega = tanhf(weights[tid * 3 + 2]);
        const float c  = cosf(theta * 0.5f);
        const float sn = sinf(theta * 0.5f);
        const float a  = 0.5f * (phi + omega);
        const float bb = 0.5f * (phi - omega);
        const float ca = cosf(a),  sa = sinf(a);
        const float cb = cosf(bb), sb = sinf(bb);
        // U00 = e^{-ia} c ; U01 = -e^{+ib} s ; U10 = e^{-ib} s ; U11 = e^{+ia} c
        ws[tid * 8 + 0] =  ca * c;  ws[tid * 8 + 1] = -sa * c;
        ws[tid * 8 + 2] = -cb * sn; ws[tid * 8 + 3] = -sb * sn;
        ws[tid * 8 + 4] =  cb * sn; ws[tid * 8 + 5] = -sb * sn;
        ws[tid * 8 + 6] =  ca * c;  ws[tid * 8 + 7] =  sa * c;
    }
    int* wsI = (int*)ws;
    if (tid < 64) {                         // gt: 8 layers x 8 t values
        const int l = tid >> 3, t = tid & 7;
        wsI[640 + tid] = perm_g(t, (l % (WIRES - 1)) + 1);
    }
    {                                       // gl: 8 layers x 128 thread bases
        const int l = tid >> 7, e = tid & 127;
        const int i0 = ((e >> 6) << 9) | ((e & 63) << 3);
        wsI[704 + tid] = perm_g(i0, (l % (WIRES - 1)) + 1);
    }
}

// DPP cross-lane move (VALU pipe, rows of 16 lanes) — validated round 9
template<int CTRL>
__device__ __forceinline__ float dppmov(float x) {
    return __int_as_float(__builtin_amdgcn_update_dpp(
        0, __float_as_int(x), CTRL, 0xF, 0xF, true));
}
#define FX1(v)  dppmov<0xB1>(v)
#define FX2(v)  dppmov<0x4E>(v)
#define FX4(v)  dppmov<0x1B>(dppmov<0x141>(v))
#define FX8(v)  dppmov<0x128>(v)
#define FX16(v) __shfl_xor((v), 16, 64)
#define FX32(v) __shfl_xor((v), 32, 64)

#define APPLY_LOCAL8(uptr, mask)                                              \
    {                                                                         \
        const float* __restrict__ u = (uptr);                                 \
        const float u00r = u[0], u00i = u[1], u01r = u[2], u01i = u[3];       \
        const float u10r = u[4], u10i = u[5], u11r = u[6], u11i = u[7];       \
        _Pragma("unroll")                                                     \
        for (int t0 = 0; t0 < 8; ++t0) {                                      \
            if (t0 & (mask)) continue;                                        \
            const int t1 = t0 | (mask);                                       \
            const float a0r = re[t0], a0i = im[t0];                           \
            const float a1r = re[t1], a1i = im[t1];                           \
            re[t0] = u00r*a0r - u00i*a0i + u01r*a1r - u01i*a1i;               \
            im[t0] = u00r*a0i + u00i*a0r + u01r*a1i + u01i*a1r;               \
            re[t1] = u10r*a0r - u10i*a0i + u11r*a1r - u11i*a1i;               \
            im[t1] = u10r*a0i + u10i*a0r + u11r*a1i + u11i*a1r;               \
        }                                                                     \
    }

#define LANE_GATE8(W, J, FETCH)                                               \
    {                                                                         \
        const float* __restrict__ u = gw + (W) * 8;                           \
        const bool hi = (lane >> (J)) & 1;                                    \
        const float c0r = hi ? u[6] : u[0], c0i = hi ? u[7] : u[1];           \
        const float c1r = hi ? u[4] : u[2], c1i = hi ? u[5] : u[3];           \
        _Pragma("unroll")                                                     \
        for (int t = 0; t < 8; ++t) {                                         \
            const float pr = FETCH(re[t]);                                    \
            const float pi = FETCH(im[t]);                                    \
            const float sr = re[t], si = im[t];                               \
            re[t] = c0r*sr - c0i*si + c1r*pr - c1i*pi;                        \
            im[t] = c0r*si + c0i*sr + c1r*pi + c1i*pr;                        \
        }                                                                     \
    }

__global__ __launch_bounds__(128) void qsim2(
    const float* __restrict__ x,
    const float* __restrict__ ws,
    float* __restrict__ out,
    const int interleaved)
{
    __shared__ float lre[NSTATE];
    __shared__ float lim[NSTATE];
    const int tid  = threadIdx.x;           // 0..127
    const int lane = tid & 63;
    const int b    = blockIdx.x;
    const int i0   = ((tid >> 6) << 9) | (lane << 3);   // base amp index
    const int* __restrict__ wsI = (const int*)ws;

    float re[8], im[8];

    // ---- load 8 contiguous amplitudes (real input, imag = 0) ----
    const float4* __restrict__ x4 =
        (const float4*)(x + ((size_t)b << 10) + i0);
    {
        const float4 v0 = x4[0], v1 = x4[1];
        re[0]=v0.x; re[1]=v0.y; re[2]=v0.z; re[3]=v0.w;
        re[4]=v1.x; re[5]=v1.y; re[6]=v1.z; re[7]=v1.w;
#pragma unroll
        for (int t = 0; t < 8; ++t) im[t] = 0.f;
    }

    for (int l = 0; l < QDEPTH; ++l) {
        const float* __restrict__ gw = ws + l * 80;

        // ---- local gates: t-bits 0,1,2 = wires 9,8,7 ----
        APPLY_LOCAL8(gw + 9*8, 1)
        APPLY_LOCAL8(gw + 8*8, 2)
        APPLY_LOCAL8(gw + 7*8, 4)

        // ---- lane-bit gates: wires 6..3 on DPP, wires 2,1 via shfl ----
        LANE_GATE8(6, 0, FX1)
        LANE_GATE8(5, 1, FX2)
        LANE_GATE8(4, 2, FX4)
        LANE_GATE8(3, 3, FX8)
        LANE_GATE8(2, 4, FX16)
        LANE_GATE8(1, 5, FX32)

        // ---- stage to LDS, lane-major (contiguous -> b128 writes) ----
        *(float4*)&lre[i0]     = make_float4(re[0], re[1], re[2], re[3]);
        *(float4*)&lre[i0 + 4] = make_float4(re[4], re[5], re[6], re[7]);
        *(float4*)&lim[i0]     = make_float4(im[0], im[1], im[2], im[3]);
        *(float4*)&lim[i0 + 4] = make_float4(im[4], im[5], im[6], im[7]);
        __syncthreads();

        // ---- wire-0 gate folded into CNOT permutation read ----
        // new[i] = c0 * psi[j] + c1 * psi[j^512], j = g(i), c's by bit9(j)
        const float* __restrict__ u0 = gw;          // wire 0 coeffs
        const int gl = wsI[704 + l * 128 + tid];    // g(i0)
#pragma unroll
        for (int t = 0; t < 8; ++t) {
            const int j  = gl ^ wsI[640 + l * 8 + t];   // g(i0|t) = g(i0)^g(t)
            const int jp = j ^ 512;
            const float sr = lre[j],  si = lim[j];
            const float pr = lre[jp], pi = lim[jp];
            const bool hib = (j >> 9) & 1;
            const float c0r = hib ? u0[6] : u0[0], c0i = hib ? u0[7] : u0[1];
            const float c1r = hib ? u0[4] : u0[2], c1i = hib ? u0[5] : u0[3];
            re[t] = c0r*sr - c0i*si + c1r*pr - c1i*pi;
            im[t] = c0r*si + c0i*sr + c1r*pi + c1i*pr;
        }
        __syncthreads();        // protect LDS from next layer's writes
    }

    // ---- epilogue ----
    if (interleaved) {
        float4* __restrict__ o4 = (float4*)(out + 2 * (((size_t)b << 10) + i0));
        o4[0] = make_float4(re[0], im[0], re[1], im[1]);
        o4[1] = make_float4(re[2], im[2], re[3], im[3]);
        o4[2] = make_float4(re[4], im[4], re[5], im[5]);
        o4[3] = make_float4(re[6], im[6], re[7], im[7]);
    } else {
        // harness compares real part only (complex64 expected cast to f32)
        float4* __restrict__ o4 = (float4*)(out + ((size_t)b << 10) + i0);
        o4[0] = make_float4(re[0], re[1], re[2], re[3]);
        o4[1] = make_float4(re[4], re[5], re[6], re[7]);
    }
}

// ---------------- validated round-6 fallback (ws too small) ----------------
__global__ __launch_bounds__(256) void qcircuit_kernel(
    const float* __restrict__ x, const float* __restrict__ weights,
    float* __restrict__ out, const int interleaved)
{
    __shared__ float s_re[NSTATE];
    __shared__ float s_im[NSTATE];
    __shared__ float s_g[NGATES][8];
    const int tid = threadIdx.x;
    const int b   = blockIdx.x;
    if (tid < NGATES) {
        const float phi   = tanhf(weights[tid * 3 + 0]);
        const float theta = tanhf(weights[tid * 3 + 1]);
        const float omega = tanhf(weights[tid * 3 + 2]);
        const float c  = cosf(theta * 0.5f);
        const float sn = sinf(theta * 0.5f);
        const float a  = 0.5f * (phi + omega);
        const float bb = 0.5f * (phi - omega);
        const float ca = cosf(a),  sa = sinf(a);
        const float cb = cosf(bb), sb = sinf(bb);
        s_g[tid][0] =  ca * c;  s_g[tid][1] = -sa * c;
        s_g[tid][2] = -cb * sn; s_g[tid][3] = -sb * sn;
        s_g[tid][4] =  cb * sn; s_g[tid][5] = -sb * sn;
        s_g[tid][6] =  ca * c;  s_g[tid][7] =  sa * c;
    }
#pragma unroll
    for (int k = 0; k < 4; ++k) {
        const int i = tid + 256 * k;
        s_re[i] = x[b * NSTATE + i];
        s_im[i] = 0.0f;
    }
    __syncthreads();
    for (int l = 0; l < QDEPTH; ++l) {
        for (int q = 0; q < WIRES; ++q) {
            const int gi = l * WIRES + q;
            const float u00r = s_g[gi][0], u00i = s_g[gi][1];
            const float u01r = s_g[gi][2], u01i = s_g[gi][3];
            const float u10r = s_g[gi][4], u10i = s_g[gi][5];
            const float u11r = s_g[gi][6], u11i = s_g[gi][7];
            const int sh = 9 - q;
            const int m  = 1 << sh;
#pragma unroll
            for (int k = 0; k < 2; ++k) {
                const int p  = tid + 256 * k;
                const int i0 = ((p >> sh) << (sh + 1)) | (p & (m - 1));
                const int i1 = i0 | m;
                const float a0r = s_re[i0], a0i = s_im[i0];
                const float a1r = s_re[i1], a1i = s_im[i1];
                s_re[i0] = u00r*a0r - u00i*a0i + u01r*a1r - u01i*a1i;
                s_im[i0] = u00r*a0i + u00i*a0r + u01r*a1i + u01i*a1r;
                s_re[i1] = u10r*a0r - u10i*a0i + u11r*a1r - u11i*a1i;
                s_im[i1] = u10r*a0i + u10i*a0r + u11r*a1i + u11i*a1r;
            }
            __syncthreads();
        }
        const int r = (l % (WIRES - 1)) + 1;
        float vr[4], vi[4];
#pragma unroll
        for (int k = 0; k < 4; ++k) {
            const int i = tid + 256 * k;
            const int j = perm_g(i, r);
            vr[k] = s_re[j]; vi[k] = s_im[j];
        }
        __syncthreads();
#pragma unroll
        for (int k = 0; k < 4; ++k) {
            const int i = tid + 256 * k;
            s_re[i] = vr[k]; s_im[i] = vi[k];
        }
        __syncthreads();
    }
    if (interleaved) {
#pragma unroll
        for (int k = 0; k < 4; ++k) {
            const int i  = tid + 256 * k;
            const int fi = 2 * (b * NSTATE + i);
            out[fi + 0] = s_re[i];
            out[fi + 1] = s_im[i];
        }
    } else {
#pragma unroll
        for (int k = 0; k < 4; ++k) {
            const int i = tid + 256 * k;
            out[b * NSTATE + i] = s_re[i];
        }
    }
}

extern "C" void kernel_launch(void* const* d_in, const int* in_sizes, int n_in,
                              void* d_out, int out_size, void* d_ws, size_t ws_size,
                              hipStream_t stream) {
    const float* x       = (const float*)d_in[0];   // (2048,1,32,32) f32
    const float* weights = (const float*)d_in[1];   // (8,10,3) f32
    float* out = (float*)d_out;
    const int interleaved = (out_size >= 2 * NBATCH * NSTATE) ? 1 : 0;

    if (ws_size >= WS_WORDS * sizeof(float)) {
        float* ws = (float*)d_ws;
        qprep<<<1, 1024, 0, stream>>>(weights, ws);
        qsim2<<<NBATCH, 128, 0, stream>>>(x, ws, out, interleaved);
    } else {
        qcircuit_kernel<<<NBATCH, 256, 0, stream>>>(x, weights, out, interleaved);
    }
}